// Round 5
// baseline (2408.016 us; speedup 1.0000x reference)
//
#include <hip/hip_runtime.h>
#include <math.h>

// Problem constants (fixed by the reference)
#define HDIM   512
#define NDIM   16
#define SEQ    64
#define TSTEPS 63
#define BATCH  256
#define ODIM   9
#define NTHR   1024    // 16 waves/CU: R4 showed fill-utilization is occupancy-limited

// R5: 1024-thread blocks (16 waves, 2x latency hiding), copy-free ping-pong
// matvec with contiguous two-segment row rotation (no per-load mask/mul, no
// register copies), one-pass LN (single fused (x, x^2) reduction).
// R4 evidence: FETCH 9KB (weights L2-resident), HBM silent, 29us/step vs
// 13.7us/step L1-fill floor (2MB @ 64B/cyc), VALU 28%, occ 24% -> stall-bound.
// Precision: f32 internals proven (R4 absmax == R3-f64 absmax, bit-identical);
// discrete decisions still via f32-sigmoid emulation of numpy (saturation!).
//
// Encoder S4 stack is dead code; only encoded = in_seq@in_W+in_b is needed.

__device__ __forceinline__ float gelu_f32(float x) {
    return 0.5f * x * (1.0f + erff(x * 0.70710678118654752440f));
}

__device__ __forceinline__ float sig32(float x) {
    return 1.0f / (1.0f + expf(-x));
}

// matvec helpers: 4-row chunks, ping-pong buffers, pointer-increment loads.
__device__ __forceinline__ void mv_load(float4 (&buf)[4], const float4* Wb, int r0) {
    const float4* p = Wb + r0 * 128;
    buf[0] = p[0]; buf[1] = p[128]; buf[2] = p[256]; buf[3] = p[384];
}
__device__ __forceinline__ void mv_fma(const float4 (&buf)[4],
                                       const float* __restrict__ gb, int r0,
                                       float& a0, float& a1, float& a2, float& a3) {
    #pragma unroll
    for (int j = 0; j < 4; ++j) {
        float gv = gb[r0 + j];
        a0 = fmaf(gv, buf[j].x, a0);
        a1 = fmaf(gv, buf[j].y, a1);
        a2 = fmaf(gv, buf[j].z, a2);
        a3 = fmaf(gv, buf[j].w, a3);
    }
}

// z[c] = sum_h g[h] * W[h][c]. 1024 thr: hq=tid>>7 in [0,8) owns 64 rows,
// cq=tid&127 owns 4 cols. rot4 (multiple of 4, per-WG) de-correlates the
// 32 same-XCD CUs' L2 line access order (this is what fixed R3's thrash).
__device__ __forceinline__ void matvec512(
    const float* __restrict__ W,           // outW + j*HDIM*HDIM, [h][c]
    const float* __restrict__ g,           // LDS (512)
    float* __restrict__ zpart,             // LDS (8*512)
    int tid, int rot4)
{
    const int hq = tid >> 7;
    const int cq = tid & 127;
    const float4* Wb = (const float4*)W + (hq * 64) * 128 + cq;
    const float*  gb = g + hq * 64;
    float4 A[4], B[4];
    float a0 = 0.f, a1 = 0.f, a2 = 0.f, a3 = 0.f;
    int r0 = rot4;
    mv_load(A, Wb, r0);
    #pragma unroll 1
    for (int c = 0; c < 14; c += 2) {
        int r1 = (rot4 + 4 * (c + 1)) & 63;
        mv_load(B, Wb, r1);
        mv_fma(A, gb, r0, a0, a1, a2, a3);
        int r2 = (rot4 + 4 * (c + 2)) & 63;
        mv_load(A, Wb, r2);
        mv_fma(B, gb, r1, a0, a1, a2, a3);
        r0 = r2;
    }
    {   // tail pair (chunks 14,15) without wasted wrap reload
        int r1 = (rot4 + 60) & 63;
        mv_load(B, Wb, r1);
        mv_fma(A, gb, r0, a0, a1, a2, a3);
        mv_fma(B, gb, r1, a0, a1, a2, a3);
    }
    *(float4*)&zpart[hq * HDIM + 4 * cq] = make_float4(a0, a1, a2, a3);
}

__global__ __launch_bounds__(NTHR, 1)
void s4_decode_kernel(
    const float* __restrict__ input_seq,   // (B,S,3)
    const float* __restrict__ in_W,        // (3,H)
    const float* __restrict__ in_b,        // (H)
    const float* __restrict__ Aarr,        // (L,H,N)
    const float* __restrict__ Barr,        // (L,H,N)
    const float* __restrict__ Carr,        // (L,H,N)
    const float* __restrict__ Darr,        // (L,H)
    const float* __restrict__ outW,        // (L,H,H)
    const float* __restrict__ outb,        // (L,H)
    const float* __restrict__ ln_g,        // (L,H)
    const float* __restrict__ ln_b,        // (L,H)
    const float* __restrict__ headW,       // (H,9)
    const float* __restrict__ headb,       // (9)
    float* __restrict__ out)               // (B,T,9)
{
    __shared__ float ld_xd[HDIM];
    __shared__ float ld_g[HDIM];
    __shared__ float ld_z[8 * HDIM];       // 16 KB partials
    __shared__ float ld_D0[HDIM];
    __shared__ float ld_D1[HDIM];
    __shared__ float ld_red[16 * ODIM];    // head partials (also LN pair red)
    __shared__ float ld_logit[ODIM + 1];
    __shared__ float ld_dec[4];
    __shared__ int   ld_ptr;

    const int b   = blockIdx.x;
    const int tid = threadIdx.x;
    const int hg  = tid >> 4;              // [0,64)
    const int n   = tid & 15;
    const int col = tid & 511;             // per-column param index (dup in upper half)
    const int rot4 = ((b * 37) & 63) & ~3; // multiple of 4

    // ---- persistent per-thread registers: states + SSM params ----
    // thread owns (h = hg + 64k, n) for k in [0,8); Aarr index = tid + 1024k.
    float s0[8], s1[8];
    float A0[8], B0[8], C0[8], A1[8], B1[8], C1[8];
    #pragma unroll
    for (int k = 0; k < 8; ++k) {
        int i0 = tid + 1024 * k;
        int i1 = 8192 + i0;
        A0[k] = Aarr[i0]; B0[k] = Barr[i0]; C0[k] = Carr[i0];
        A1[k] = Aarr[i1]; B1[k] = Barr[i1]; C1[k] = Carr[i1];
        s0[k] = 0.f; s1[k] = 0.f;
    }

    // per-column constants
    const float inb_t = in_b[col];
    const float w0 = in_W[col], w1 = in_W[HDIM + col], w2 = in_W[2 * HDIM + col];
    const float ob0 = outb[col], ob1 = outb[HDIM + col];
    const float lg0 = ln_g[col], lg1 = ln_g[HDIM + col];
    const float lb0 = ln_b[col], lb1 = ln_b[HDIM + col];

    if (tid < HDIM) { ld_D0[tid] = Darr[tid]; ld_D1[tid] = Darr[HDIM + tid]; }
    float ctxr = 0.f;
    if (tid == 0) { ld_dec[0] = 0.f; ld_dec[1] = 0.f; ld_dec[2] = 1.f; }
    __syncthreads();

    for (int i = 0; i < TSTEPS; ++i) {
        // ---- decoder input projection ----
        float dpv = fmaf(ld_dec[0], w0, fmaf(ld_dec[1], w1, fmaf(ld_dec[2], w2, inb_t)));
        if (tid < HDIM) ld_xd[tid] = dpv;
        __syncthreads();

        #pragma unroll 1
        for (int blk = 0; blk < 2; ++blk) {
            // ---- S4 state update + gelu -> g ----
            {
                float* s  = blk ? s1 : s0;
                float* Ar = blk ? A1 : A0;
                float* Br = blk ? B1 : B0;
                float* Cr = blk ? C1 : C0;
                const float* Dl = blk ? ld_D1 : ld_D0;
                #pragma unroll
                for (int k = 0; k < 8; ++k) {
                    int h = hg + 64 * k;
                    float xh = ld_xd[h];
                    float sv = fmaf(Ar[k], s[k], Br[k] * xh);
                    s[k] = sv;
                    float p = sv * Cr[k];
                    p += __shfl_xor(p, 1);
                    p += __shfl_xor(p, 2);
                    p += __shfl_xor(p, 4);
                    p += __shfl_xor(p, 8);
                    if (n == 0) ld_g[h] = gelu_f32(p + Dl[h] * xh);
                }
            }
            __syncthreads();
            // ---- matvec ----
            matvec512(outW + blk * HDIM * HDIM, ld_g, ld_z, tid, rot4);
            __syncthreads();
            // ---- residual + one-pass LN ----
            {
                float tmp = 0.f;
                if (tid < HDIM) {
                    float z = ld_z[tid] + ld_z[HDIM + tid] + ld_z[2*HDIM + tid]
                            + ld_z[3*HDIM + tid] + ld_z[4*HDIM + tid]
                            + ld_z[5*HDIM + tid] + ld_z[6*HDIM + tid]
                            + ld_z[7*HDIM + tid] + (blk ? ob1 : ob0);
                    float res = (i == 0) ? dpv : z;   // ref: residual=proj @ i==0
                    tmp = z + res;
                }
                float v1 = tmp, v2 = tmp * tmp;
                #pragma unroll
                for (int m = 1; m < 64; m <<= 1) {
                    v1 += __shfl_xor(v1, m);
                    v2 += __shfl_xor(v2, m);
                }
                if ((tid & 63) == 0) {
                    ld_red[2 * (tid >> 6)]     = v1;
                    ld_red[2 * (tid >> 6) + 1] = v2;
                }
                __syncthreads();
                float s1r = 0.f, s2r = 0.f;
                #pragma unroll
                for (int q = 0; q < 16; ++q) { s1r += ld_red[2*q]; s2r += ld_red[2*q+1]; }
                float mu  = s1r * (1.f / 512.f);
                float var = s2r * (1.f / 512.f) - mu * mu;
                float rs  = rsqrtf(var + 1e-5f);
                __syncthreads();           // red consumed; xd safe to overwrite
                if (tid < HDIM)
                    ld_xd[tid] = (tmp - mu) * rs * (blk ? lg1 : lg0) + (blk ? lb1 : lb0);
                __syncthreads();
            }
        }

        // ================= head #1 =================
        {
            float v = (tid < HDIM) ? (ld_xd[tid] + ctxr) : 0.f;
            const float* w = headW + col * ODIM;
            float p[ODIM];
            #pragma unroll
            for (int o = 0; o < ODIM; ++o) p[o] = v * w[o];
            #pragma unroll
            for (int m = 1; m < 64; m <<= 1) {
                #pragma unroll
                for (int o = 0; o < ODIM; ++o) p[o] += __shfl_xor(p[o], m);
            }
            if ((tid & 63) == 0) {
                int wv = tid >> 6;
                #pragma unroll
                for (int o = 0; o < ODIM; ++o) ld_red[wv * ODIM + o] = p[o];
            }
            __syncthreads();
            if (tid < ODIM) {
                float s = headb[tid];
                #pragma unroll
                for (int wv = 0; wv < 16; ++wv) s += ld_red[wv * ODIM + tid];
                ld_logit[tid] = s;
            }
            __syncthreads();
        }

        const bool is_out = ((i & 1) == 0);
        if (is_out) {
            if (tid < ODIM)
                out[(b * TSTEPS + i) * ODIM + tid] = sig32(ld_logit[tid]);
            if (tid == 0) {
                float nc = (sig32(ld_logit[0]) > 0.5f) ? 1.f : 0.f;
                ld_dec[0] = nc; ld_dec[1] = 1.f; ld_dec[2] = 0.f;
            }
            __syncthreads();
        } else {
            // np.argmax over f32 SIGMOIDS (saturation => not logit-argmax!)
            if (tid == 0) {
                int best = 0; float bv = sig32(ld_logit[3]);
                #pragma unroll
                for (int o = 1; o < 6; ++o) {
                    float v2 = sig32(ld_logit[3 + o]);
                    if (v2 > bv) { bv = v2; best = o; }
                }
                ld_ptr = best;
                ld_dec[0] = 0.f; ld_dec[1] = 0.f; ld_dec[2] = 1.f;
            }
            __syncthreads();
            {   // ctx += encoded[b, ptr, :]
                const float* iseq = input_seq + (b * SEQ + ld_ptr) * 3;
                float e0 = iseq[0], e1 = iseq[1], e2 = iseq[2];
                ctxr += fmaf(e0, w0, fmaf(e1, w1, fmaf(e2, w2, inb_t)));
            }
            __syncthreads();
            // ================= head #2 =================
            {
                float v = (tid < HDIM) ? (ld_xd[tid] + ctxr) : 0.f;
                const float* w = headW + col * ODIM;
                float p[ODIM];
                #pragma unroll
                for (int o = 0; o < ODIM; ++o) p[o] = v * w[o];
                #pragma unroll
                for (int m = 1; m < 64; m <<= 1) {
                    #pragma unroll
                    for (int o = 0; o < ODIM; ++o) p[o] += __shfl_xor(p[o], m);
                }
                if ((tid & 63) == 0) {
                    int wv = tid >> 6;
                    #pragma unroll
                    for (int o = 0; o < ODIM; ++o) ld_red[wv * ODIM + o] = p[o];
                }
                __syncthreads();
                if (tid < ODIM) {
                    float s = headb[tid];
                    #pragma unroll
                    for (int wv = 0; wv < 16; ++wv) s += ld_red[wv * ODIM + tid];
                    out[(b * TSTEPS + i) * ODIM + tid] = sig32(s);
                }
            }
            __syncthreads();
        }
    }
}

extern "C" void kernel_launch(void* const* d_in, const int* in_sizes, int n_in,
                              void* d_out, int out_size, void* d_ws, size_t ws_size,
                              hipStream_t stream) {
    (void)in_sizes; (void)n_in; (void)d_ws; (void)ws_size; (void)out_size;
    const float* input_seq = (const float*)d_in[0];
    // d_in[1] = autoregressive_steps (scalar) -- T fixed at 63 by the model
    const float* in_W   = (const float*)d_in[2];
    const float* in_b   = (const float*)d_in[3];
    const float* Aarr   = (const float*)d_in[4];
    const float* Barr   = (const float*)d_in[5];
    const float* Carr   = (const float*)d_in[6];
    const float* Darr   = (const float*)d_in[7];
    const float* outW   = (const float*)d_in[8];
    const float* outb   = (const float*)d_in[9];
    const float* ln_g   = (const float*)d_in[10];
    const float* ln_b   = (const float*)d_in[11];
    const float* headW  = (const float*)d_in[12];
    const float* headb  = (const float*)d_in[13];
    float* out = (float*)d_out;

    s4_decode_kernel<<<BATCH, NTHR, 0, stream>>>(
        input_seq, in_W, in_b, Aarr, Barr, Carr, Darr,
        outW, outb, ln_g, ln_b, headW, headb, out);
}

// Round 6
// 1550.097 us; speedup vs baseline: 1.5535x; 1.5535x over previous
//
#include <hip/hip_runtime.h>
#include <math.h>

// Problem constants (fixed by the reference)
#define HDIM   512
#define NDIM   16
#define SEQ    64
#define TSTEPS 63
#define BATCH  256
#define ODIM   9
#define NTHR   512

// R6: 4-WG cooperative weight sharing. R4's limiter = per-CU 2MB/step L2
// weight stream (invariant under batch-parallel). Groups of 4 WGs (batches
// {b0, b0+8, b0+16, b0+24}: same XCD under round-robin) column-slice outW:
// each WG streams W[:, 128 cols] (1/4 traffic) for all 4 batches' g vectors.
// g/z exchanged via d_ws mailbox using RELAXED agent-scope atomics (coherent
// across XCDs without acquire/release cache invalidates -> weight L2
// residency preserved; correctness does not depend on XCD mapping).
// Ordering: data stores drained by __syncthreads (vmcnt0 before s_barrier),
// then thread0 publishes flag; readers spin on flag then issue atomic loads.
// Single-buffer mailbox is hazard-free via the 2-phase flag transitivity.
// R5 lesson: 1024thr/__launch_bounds__(1024,1) -> compiler capped VGPR=64 ->
// scratch spill = 1.7GB HBM. Stay at 512 thr, (512,2).
//
// Encoder S4 stack is dead code; only encoded = in_seq@in_W+in_b is needed.
// Discrete decisions via f32-sigmoid emulation of numpy (saturation!).

__device__ __forceinline__ float gelu_f32(float x) {
    return 0.5f * x * (1.0f + erff(x * 0.70710678118654752440f));
}

__device__ __forceinline__ float sig32(float x) {
    return 1.0f / (1.0f + expf(-x));
}

__global__ __launch_bounds__(NTHR, 2)
void s4_decode_kernel(
    const float* __restrict__ input_seq,   // (B,S,3)
    const float* __restrict__ in_W,        // (3,H)
    const float* __restrict__ in_b,        // (H)
    const float* __restrict__ Aarr,        // (L,H,N)
    const float* __restrict__ Barr,        // (L,H,N)
    const float* __restrict__ Carr,        // (L,H,N)
    const float* __restrict__ Darr,        // (L,H)
    const float* __restrict__ outW,        // (L,H,H)
    const float* __restrict__ outb,        // (L,H)
    const float* __restrict__ ln_g,        // (L,H)
    const float* __restrict__ ln_b,        // (L,H)
    const float* __restrict__ headW,       // (H,9)
    const float* __restrict__ headb,       // (9)
    float* __restrict__ out,               // (B,T,9)
    float* gws, float* zws,                // mailboxes: (256,512) each
    unsigned* fg, unsigned* fz)            // flags: (256) each, zeroed/launch
{
    __shared__ float  ld_xd[HDIM];
    __shared__ float  ld_gall[4 * HDIM];   // g for the 4 group batches
    __shared__ float4 ld_z4[16 * 4 * 32];  // 32 KB matvec partials
    __shared__ float  ld_D0[HDIM];
    __shared__ float  ld_D1[HDIM];
    __shared__ float  ld_red[16];          // LN (v1,v2) per wave
    __shared__ float  ld_hred[8 * ODIM];   // head partials
    __shared__ float  ld_logit[ODIM + 1];
    __shared__ float  ld_dec[4];
    __shared__ int    ld_ptr;

    const int b    = blockIdx.x;
    const int tid  = threadIdx.x;
    const int hg   = tid >> 4;             // [0,32) for state phase
    const int n    = tid & 15;
    const int mem  = (b >> 3) & 3;         // slot in 4-WG group
    const int gbase = b - 8 * mem;         // group batches: gbase + 8j
    // matvec assignment: c4 = float4-col within my 128-col slice, rg = row group
    const int c4   = tid & 31;
    const int rg   = tid >> 5;             // [0,16)
    const int rgE  = (rg + ((b * 5) & 15)) & 15;  // per-WG row rotation
    const int base_row = rgE * 32;

    // ---- persistent per-thread registers: states + SSM params (R4 layout) ----
    float s0[16], s1[16];
    float A0[16], B0[16], C0[16], A1[16], B1[16], C1[16];
    #pragma unroll
    for (int k = 0; k < 16; ++k) {
        int h  = hg + 32 * k;
        int i0 = h * NDIM + n;
        int i1 = (HDIM + h) * NDIM + n;
        A0[k] = Aarr[i0]; B0[k] = Barr[i0]; C0[k] = Carr[i0];
        A1[k] = Aarr[i1]; B1[k] = Barr[i1]; C1[k] = Carr[i1];
        s0[k] = 0.f; s1[k] = 0.f;
    }

    // per-column constants
    const float inb_t = in_b[tid];
    const float w0 = in_W[tid], w1 = in_W[HDIM + tid], w2 = in_W[2 * HDIM + tid];
    const float ob0 = outb[tid], ob1 = outb[HDIM + tid];
    const float lg0 = ln_g[tid], lg1 = ln_g[HDIM + tid];
    const float lb0 = ln_b[tid], lb1 = ln_b[HDIM + tid];

    ld_D0[tid] = Darr[tid];
    ld_D1[tid] = Darr[HDIM + tid];

    // weight base for my column slice (float4 granularity)
    const float4* Wsl = (const float4*)outW + mem * 32 + c4;

    float ctxr = 0.f;
    if (tid == 0) { ld_dec[0] = 0.f; ld_dec[1] = 0.f; ld_dec[2] = 1.f; }
    __syncthreads();

    for (int i = 0; i < TSTEPS; ++i) {
        // ---- decoder input projection ----
        float dpv = fmaf(ld_dec[0], w0, fmaf(ld_dec[1], w1, fmaf(ld_dec[2], w2, inb_t)));
        __syncthreads();                   // ld_dec consumed
        ld_xd[tid] = dpv;
        __syncthreads();

        #pragma unroll 1
        for (int blk = 0; blk < 2; ++blk) {
            const unsigned seq = (unsigned)(2 * i + blk + 1);
            // ---- S4 state update + gelu -> own slot of ld_gall ----
            {
                float* s  = blk ? s1 : s0;
                float* Ar = blk ? A1 : A0;
                float* Br = blk ? B1 : B0;
                float* Cr = blk ? C1 : C0;
                const float* Dl = blk ? ld_D1 : ld_D0;
                #pragma unroll
                for (int k = 0; k < 16; ++k) {
                    int h = hg + 32 * k;
                    float xh = ld_xd[h];
                    float sv = fmaf(Ar[k], s[k], Br[k] * xh);
                    s[k] = sv;
                    float p = sv * Cr[k];
                    p += __shfl_xor(p, 1);
                    p += __shfl_xor(p, 2);
                    p += __shfl_xor(p, 4);
                    p += __shfl_xor(p, 8);
                    if (n == 0) ld_gall[mem * HDIM + h] = gelu_f32(p + Dl[h] * xh);
                }
            }
            __syncthreads();
            // ---- publish own g (atomic stores perform at coherence point) ----
            __hip_atomic_store(&gws[b * HDIM + tid], ld_gall[mem * HDIM + tid],
                               __ATOMIC_RELAXED, __HIP_MEMORY_SCOPE_AGENT);
            __syncthreads();               // drains vmcnt before barrier exit
            if (tid == 0) {
                __hip_atomic_store(&fg[b], seq, __ATOMIC_RELAXED, __HIP_MEMORY_SCOPE_AGENT);
                #pragma unroll
                for (int j = 0; j < 4; ++j) {
                    if (j == mem) continue;
                    while (__hip_atomic_load(&fg[gbase + 8 * j],
                                             __ATOMIC_RELAXED, __HIP_MEMORY_SCOPE_AGENT) < seq)
                        __builtin_amdgcn_s_sleep(1);
                }
            }
            __syncthreads();
            // ---- fetch the 3 foreign g vectors ----
            #pragma unroll
            for (int j = 0; j < 4; ++j) {
                if (j == mem) continue;
                ld_gall[j * HDIM + tid] =
                    __hip_atomic_load(&gws[(gbase + 8 * j) * HDIM + tid],
                                      __ATOMIC_RELAXED, __HIP_MEMORY_SCOPE_AGENT);
            }
            __syncthreads();
            // ---- matvec: my 128-col slice x 4 batches, rotated 32-row window ----
            {
                const float4* Wb = Wsl + (size_t)blk * HDIM * 128;
                float4 acc[4];
                #pragma unroll
                for (int bi = 0; bi < 4; ++bi) acc[bi] = make_float4(0.f, 0.f, 0.f, 0.f);
                float4 a0 = Wb[(size_t)(base_row)     * 128];
                float4 a1 = Wb[(size_t)(base_row + 1) * 128];
                #pragma unroll 2
                for (int rr = 0; rr < 32; rr += 4) {
                    int rB = base_row + ((rr + 2) & 31);
                    float4 b0 = Wb[(size_t)rB * 128];
                    float4 b1 = Wb[(size_t)(rB + 1) * 128];
                    {
                        int r = base_row + rr;
                        #pragma unroll
                        for (int bi = 0; bi < 4; ++bi) {
                            float g0 = ld_gall[bi * HDIM + r];
                            float g1 = ld_gall[bi * HDIM + r + 1];
                            acc[bi].x = fmaf(g1, a1.x, fmaf(g0, a0.x, acc[bi].x));
                            acc[bi].y = fmaf(g1, a1.y, fmaf(g0, a0.y, acc[bi].y));
                            acc[bi].z = fmaf(g1, a1.z, fmaf(g0, a0.z, acc[bi].z));
                            acc[bi].w = fmaf(g1, a1.w, fmaf(g0, a0.w, acc[bi].w));
                        }
                    }
                    int rA = base_row + ((rr + 4) & 31);
                    a0 = Wb[(size_t)rA * 128];
                    a1 = Wb[(size_t)(rA + 1) * 128];
                    {
                        int r = base_row + rr + 2;
                        #pragma unroll
                        for (int bi = 0; bi < 4; ++bi) {
                            float g0 = ld_gall[bi * HDIM + r];
                            float g1 = ld_gall[bi * HDIM + r + 1];
                            acc[bi].x = fmaf(g1, b1.x, fmaf(g0, b0.x, acc[bi].x));
                            acc[bi].y = fmaf(g1, b1.y, fmaf(g0, b0.y, acc[bi].y));
                            acc[bi].z = fmaf(g1, b1.z, fmaf(g0, b0.z, acc[bi].z));
                            acc[bi].w = fmaf(g1, b1.w, fmaf(g0, b0.w, acc[bi].w));
                        }
                    }
                }
                #pragma unroll
                for (int bi = 0; bi < 4; ++bi)
                    ld_z4[(rg * 4 + bi) * 32 + c4] = acc[bi];
            }
            __syncthreads();
            // ---- reduce 16 row-group partials, ship slices to owners ----
            {
                const float* zf = (const float*)ld_z4;
                int bi2 = tid >> 7;        // group member index
                int col = tid & 127;
                float zv = 0.f;
                #pragma unroll
                for (int k = 0; k < 16; ++k) zv += zf[(k * 4 + bi2) * 128 + col];
                __hip_atomic_store(&zws[(gbase + 8 * bi2) * HDIM + mem * 128 + col], zv,
                                   __ATOMIC_RELAXED, __HIP_MEMORY_SCOPE_AGENT);
            }
            __syncthreads();
            if (tid == 0) {
                __hip_atomic_store(&fz[b], seq, __ATOMIC_RELAXED, __HIP_MEMORY_SCOPE_AGENT);
                #pragma unroll
                for (int j = 0; j < 4; ++j) {
                    if (j == mem) continue;
                    while (__hip_atomic_load(&fz[gbase + 8 * j],
                                             __ATOMIC_RELAXED, __HIP_MEMORY_SCOPE_AGENT) < seq)
                        __builtin_amdgcn_s_sleep(1);
                }
            }
            __syncthreads();
            // ---- read own full z, residual + one-pass LN ----
            {
                float z = __hip_atomic_load(&zws[b * HDIM + tid],
                                            __ATOMIC_RELAXED, __HIP_MEMORY_SCOPE_AGENT)
                        + (blk ? ob1 : ob0);
                float res = (i == 0) ? dpv : z;    // ref: residual=proj @ i==0
                float tmp = z + res;
                float v1 = tmp, v2 = tmp * tmp;
                #pragma unroll
                for (int m = 1; m < 64; m <<= 1) {
                    v1 += __shfl_xor(v1, m);
                    v2 += __shfl_xor(v2, m);
                }
                if ((tid & 63) == 0) {
                    ld_red[2 * (tid >> 6)]     = v1;
                    ld_red[2 * (tid >> 6) + 1] = v2;
                }
                __syncthreads();
                float s1r = 0.f, s2r = 0.f;
                #pragma unroll
                for (int q = 0; q < 8; ++q) { s1r += ld_red[2*q]; s2r += ld_red[2*q+1]; }
                float mu  = s1r * (1.f / 512.f);
                float var = s2r * (1.f / 512.f) - mu * mu;
                float rs  = rsqrtf(var + 1e-5f);
                __syncthreads();           // red consumed; xd safe to overwrite
                ld_xd[tid] = (tmp - mu) * rs * (blk ? lg1 : lg0) + (blk ? lb1 : lb0);
                __syncthreads();
            }
        }

        // ================= head #1 =================
        {
            float v = ld_xd[tid] + ctxr;
            const float* w = headW + tid * ODIM;
            float p[ODIM];
            #pragma unroll
            for (int o = 0; o < ODIM; ++o) p[o] = v * w[o];
            #pragma unroll
            for (int m = 1; m < 64; m <<= 1) {
                #pragma unroll
                for (int o = 0; o < ODIM; ++o) p[o] += __shfl_xor(p[o], m);
            }
            if ((tid & 63) == 0) {
                int wv = tid >> 6;
                #pragma unroll
                for (int o = 0; o < ODIM; ++o) ld_hred[wv * ODIM + o] = p[o];
            }
            __syncthreads();
            if (tid < ODIM) {
                float s = headb[tid];
                #pragma unroll
                for (int wv = 0; wv < 8; ++wv) s += ld_hred[wv * ODIM + tid];
                ld_logit[tid] = s;
            }
            __syncthreads();
        }

        const bool is_out = ((i & 1) == 0);
        if (is_out) {
            if (tid < ODIM)
                out[(b * TSTEPS + i) * ODIM + tid] = sig32(ld_logit[tid]);
            if (tid == 0) {
                float nc = (sig32(ld_logit[0]) > 0.5f) ? 1.f : 0.f;
                ld_dec[0] = nc; ld_dec[1] = 1.f; ld_dec[2] = 0.f;
            }
            __syncthreads();
        } else {
            // np.argmax over f32 SIGMOIDS (saturation => not logit-argmax!)
            if (tid == 0) {
                int best = 0; float bv = sig32(ld_logit[3]);
                #pragma unroll
                for (int o = 1; o < 6; ++o) {
                    float v2 = sig32(ld_logit[3 + o]);
                    if (v2 > bv) { bv = v2; best = o; }
                }
                ld_ptr = best;
                ld_dec[0] = 0.f; ld_dec[1] = 0.f; ld_dec[2] = 1.f;
            }
            __syncthreads();
            {   // ctx += encoded[b, ptr, :]
                const float* iseq = input_seq + (b * SEQ + ld_ptr) * 3;
                float e0 = iseq[0], e1 = iseq[1], e2 = iseq[2];
                ctxr += fmaf(e0, w0, fmaf(e1, w1, fmaf(e2, w2, inb_t)));
            }
            __syncthreads();
            // ================= head #2 =================
            {
                float v = ld_xd[tid] + ctxr;
                const float* w = headW + tid * ODIM;
                float p[ODIM];
                #pragma unroll
                for (int o = 0; o < ODIM; ++o) p[o] = v * w[o];
                #pragma unroll
                for (int m = 1; m < 64; m <<= 1) {
                    #pragma unroll
                    for (int o = 0; o < ODIM; ++o) p[o] += __shfl_xor(p[o], m);
                }
                if ((tid & 63) == 0) {
                    int wv = tid >> 6;
                    #pragma unroll
                    for (int o = 0; o < ODIM; ++o) ld_hred[wv * ODIM + o] = p[o];
                }
                __syncthreads();
                if (tid < ODIM) {
                    float s = headb[tid];
                    #pragma unroll
                    for (int wv = 0; wv < 8; ++wv) s += ld_hred[wv * ODIM + tid];
                    out[(b * TSTEPS + i) * ODIM + tid] = sig32(s);
                }
            }
            __syncthreads();
        }
    }
}

extern "C" void kernel_launch(void* const* d_in, const int* in_sizes, int n_in,
                              void* d_out, int out_size, void* d_ws, size_t ws_size,
                              hipStream_t stream) {
    (void)in_sizes; (void)n_in; (void)ws_size; (void)out_size;
    const float* input_seq = (const float*)d_in[0];
    // d_in[1] = autoregressive_steps (scalar) -- T fixed at 63 by the model
    const float* in_W   = (const float*)d_in[2];
    const float* in_b   = (const float*)d_in[3];
    const float* Aarr   = (const float*)d_in[4];
    const float* Barr   = (const float*)d_in[5];
    const float* Carr   = (const float*)d_in[6];
    const float* Darr   = (const float*)d_in[7];
    const float* outW   = (const float*)d_in[8];
    const float* outb   = (const float*)d_in[9];
    const float* ln_g   = (const float*)d_in[10];
    const float* ln_b   = (const float*)d_in[11];
    const float* headW  = (const float*)d_in[12];
    const float* headb  = (const float*)d_in[13];
    float* out = (float*)d_out;

    // workspace layout: [0,1KB) fg, [1KB,2KB) fz, [4KB..) gws, zws
    unsigned* fg = (unsigned*)d_ws;
    unsigned* fz = fg + BATCH;
    float* gws = (float*)((char*)d_ws + 4096);
    float* zws = gws + BATCH * HDIM;

    // zero the flags every launch (ws is poisoned 0xAA by the harness)
    hipMemsetAsync(d_ws, 0, 4096, stream);

    s4_decode_kernel<<<BATCH, NTHR, 0, stream>>>(
        input_seq, in_W, in_b, Aarr, Barr, Carr, Darr,
        outW, outb, ln_g, ln_b, headW, headb, out,
        gws, zws, fg, fz);
}

// Round 7
// 1363.100 us; speedup vs baseline: 1.7666x; 1.1372x over previous
//
#include <hip/hip_runtime.h>
#include <math.h>

// Problem constants (fixed by the reference)
#define HDIM   512
#define NDIM   16
#define SEQ    64
#define TSTEPS 63
#define BATCH  256
#define ODIM   9
#define NTHR   512

// R7: L2 fast-path mailbox. R6 evidence: mailbox agent-atomics bypass XCD L2
// (FETCH 78MB / WRITE 144MB == mailbox volume hitting L3/HBM); 4 exchanges x
// ~5.5K cyc = ~25K of the 59K cyc/step. Fix: groups verify at runtime (via
// HW_REG_XCC_ID handshake) that all 4 members share an XCD; if so, exchange
// data via plain stores (write-through L1 -> L2, drained by __syncthreads'
// vmcnt0) + sc0 loads (L1-bypass, L2-coherent). Flags remain agent-scope.
// If ids mismatch -> R6 agent-atomic path (correct under ANY XCD mapping).
// Also: parallel flag polling (3 threads, one flag each).
// R5 lesson: keep 512 thr / __launch_bounds__(512,2) (VGPR cap -> spill).
//
// Encoder S4 stack is dead code; only encoded = in_seq@in_W+in_b is needed.
// Discrete decisions via f32-sigmoid emulation of numpy (saturation!).

__device__ __forceinline__ float gelu_f32(float x) {
    return 0.5f * x * (1.0f + erff(x * 0.70710678118654752440f));
}

__device__ __forceinline__ float sig32(float x) {
    return 1.0f / (1.0f + expf(-x));
}

// L2-coherent loads: sc0 bypasses the (possibly stale) per-CU L1 and reads
// the XCD-shared L2, where same-XCD producers' write-through stores landed.
// waitcnt inside the asm: the compiler doesn't know the outputs need a wait.
__device__ __forceinline__ void load3_l2(const float* p0, const float* p1,
                                         const float* p2,
                                         float& v0, float& v1, float& v2) {
    asm volatile(
        "global_load_dword %0, %3, off sc0\n\t"
        "global_load_dword %1, %4, off sc0\n\t"
        "global_load_dword %2, %5, off sc0\n\t"
        "s_waitcnt vmcnt(0)"
        : "=&v"(v0), "=&v"(v1), "=&v"(v2)
        : "v"(p0), "v"(p1), "v"(p2)
        : "memory");
}
__device__ __forceinline__ float load1_l2(const float* p) {
    float v;
    asm volatile("global_load_dword %0, %1, off sc0\n\t"
                 "s_waitcnt vmcnt(0)"
                 : "=v"(v) : "v"(p) : "memory");
    return v;
}

__global__ __launch_bounds__(NTHR, 2)
void s4_decode_kernel(
    const float* __restrict__ input_seq,   // (B,S,3)
    const float* __restrict__ in_W,        // (3,H)
    const float* __restrict__ in_b,        // (H)
    const float* __restrict__ Aarr,        // (L,H,N)
    const float* __restrict__ Barr,        // (L,H,N)
    const float* __restrict__ Carr,        // (L,H,N)
    const float* __restrict__ Darr,        // (L,H)
    const float* __restrict__ outW,        // (L,H,H)
    const float* __restrict__ outb,        // (L,H)
    const float* __restrict__ ln_g,        // (L,H)
    const float* __restrict__ ln_b,        // (L,H)
    const float* __restrict__ headW,       // (H,9)
    const float* __restrict__ headb,       // (9)
    float* __restrict__ out,               // (B,T,9)
    float* gws, float* zws,                // mailboxes: (256,512) each
    unsigned* fg, unsigned* fz,            // flags: (256) each, zeroed/launch
    unsigned* fx, unsigned* xid)           // XCD handshake, zeroed/launch
{
    __shared__ float  ld_xd[HDIM];
    __shared__ float  ld_gall[4 * HDIM];   // g for the 4 group batches
    __shared__ float4 ld_z4[16 * 4 * 32];  // 32 KB matvec partials
    __shared__ float  ld_D0[HDIM];
    __shared__ float  ld_D1[HDIM];
    __shared__ float  ld_red[16];          // LN (v1,v2) per wave
    __shared__ float  ld_hred[8 * ODIM];   // head partials
    __shared__ float  ld_logit[ODIM + 1];
    __shared__ float  ld_dec[4];
    __shared__ int    ld_ptr;
    __shared__ int    ld_fast;

    const int b    = blockIdx.x;
    const int tid  = threadIdx.x;
    const int hg   = tid >> 4;             // [0,32) for state phase
    const int n    = tid & 15;
    const int mem  = (b >> 3) & 3;         // slot in 4-WG group
    const int gbase = b - 8 * mem;         // group batches: gbase + 8j
    const int c4   = tid & 31;
    const int rg   = tid >> 5;             // [0,16)
    const int rgE  = (rg + ((b * 5) & 15)) & 15;  // per-WG row rotation
    const int base_row = rgE * 32;
    // foreign member indices {0..3}\{mem}
    const int j0 = 0 + (0 >= mem), j1 = 1 + (1 >= mem), j2 = 2 + (2 >= mem);

    // ---- XCD-id handshake: L2 fast path only if all 4 members co-XCD ----
    unsigned myxcd;
    asm volatile("s_getreg_b32 %0, hwreg(HW_REG_XCC_ID)" : "=s"(myxcd));
    if (tid == 0) {
        __hip_atomic_store(&xid[b], myxcd, __ATOMIC_RELAXED, __HIP_MEMORY_SCOPE_AGENT);
        __hip_atomic_store(&fx[b], 1u, __ATOMIC_RELEASE, __HIP_MEMORY_SCOPE_AGENT);
        unsigned ok = 1;
        #pragma unroll
        for (int j = 0; j < 4; ++j) {
            if (j == mem) continue;
            while (__hip_atomic_load(&fx[gbase + 8 * j],
                                     __ATOMIC_ACQUIRE, __HIP_MEMORY_SCOPE_AGENT) == 0)
                __builtin_amdgcn_s_sleep(1);
            ok &= (__hip_atomic_load(&xid[gbase + 8 * j],
                                     __ATOMIC_RELAXED, __HIP_MEMORY_SCOPE_AGENT) == myxcd);
        }
        ld_fast = (int)ok;
    }

    // ---- persistent per-thread registers: states + SSM params ----
    float s0[16], s1[16];
    float A0[16], B0[16], C0[16], A1[16], B1[16], C1[16];
    #pragma unroll
    for (int k = 0; k < 16; ++k) {
        int h  = hg + 32 * k;
        int i0 = h * NDIM + n;
        int i1 = (HDIM + h) * NDIM + n;
        A0[k] = Aarr[i0]; B0[k] = Barr[i0]; C0[k] = Carr[i0];
        A1[k] = Aarr[i1]; B1[k] = Barr[i1]; C1[k] = Carr[i1];
        s0[k] = 0.f; s1[k] = 0.f;
    }

    // per-column constants
    const float inb_t = in_b[tid];
    const float w0 = in_W[tid], w1 = in_W[HDIM + tid], w2 = in_W[2 * HDIM + tid];
    const float ob0 = outb[tid], ob1 = outb[HDIM + tid];
    const float lg0 = ln_g[tid], lg1 = ln_g[HDIM + tid];
    const float lb0 = ln_b[tid], lb1 = ln_b[HDIM + tid];

    ld_D0[tid] = Darr[tid];
    ld_D1[tid] = Darr[HDIM + tid];

    const float4* Wsl = (const float4*)outW + mem * 32 + c4;

    float ctxr = 0.f;
    if (tid == 0) { ld_dec[0] = 0.f; ld_dec[1] = 0.f; ld_dec[2] = 1.f; }
    __syncthreads();
    const bool fast = (ld_fast != 0);      // wave-uniform

    for (int i = 0; i < TSTEPS; ++i) {
        // ---- decoder input projection ----
        float dpv = fmaf(ld_dec[0], w0, fmaf(ld_dec[1], w1, fmaf(ld_dec[2], w2, inb_t)));
        __syncthreads();                   // ld_dec consumed
        ld_xd[tid] = dpv;
        __syncthreads();

        #pragma unroll 1
        for (int blk = 0; blk < 2; ++blk) {
            const unsigned seq = (unsigned)(2 * i + blk + 1);
            // ---- S4 state update + gelu -> own slot of ld_gall ----
            {
                float* s  = blk ? s1 : s0;
                float* Ar = blk ? A1 : A0;
                float* Br = blk ? B1 : B0;
                float* Cr = blk ? C1 : C0;
                const float* Dl = blk ? ld_D1 : ld_D0;
                #pragma unroll
                for (int k = 0; k < 16; ++k) {
                    int h = hg + 32 * k;
                    float xh = ld_xd[h];
                    float sv = fmaf(Ar[k], s[k], Br[k] * xh);
                    s[k] = sv;
                    float p = sv * Cr[k];
                    p += __shfl_xor(p, 1);
                    p += __shfl_xor(p, 2);
                    p += __shfl_xor(p, 4);
                    p += __shfl_xor(p, 8);
                    if (n == 0) ld_gall[mem * HDIM + h] = gelu_f32(p + Dl[h] * xh);
                }
            }
            __syncthreads();
            // ---- publish own g ----
            if (fast) {
                gws[b * HDIM + tid] = ld_gall[mem * HDIM + tid];
            } else {
                __hip_atomic_store(&gws[b * HDIM + tid], ld_gall[mem * HDIM + tid],
                                   __ATOMIC_RELAXED, __HIP_MEMORY_SCOPE_AGENT);
            }
            __syncthreads();               // drains vmcnt -> data in L2/L3
            if (tid == 4)
                __hip_atomic_store(&fg[b], seq, __ATOMIC_RELAXED, __HIP_MEMORY_SCOPE_AGENT);
            if (tid < 3) {                 // parallel polling, one flag each
                int j = tid + (tid >= mem ? 1 : 0);
                while (__hip_atomic_load(&fg[gbase + 8 * j],
                                         __ATOMIC_RELAXED, __HIP_MEMORY_SCOPE_AGENT) < seq)
                    __builtin_amdgcn_s_sleep(1);
            }
            __syncthreads();
            // ---- fetch the 3 foreign g vectors ----
            if (fast) {
                float v0, v1, v2;
                load3_l2(&gws[(gbase + 8 * j0) * HDIM + tid],
                         &gws[(gbase + 8 * j1) * HDIM + tid],
                         &gws[(gbase + 8 * j2) * HDIM + tid], v0, v1, v2);
                ld_gall[j0 * HDIM + tid] = v0;
                ld_gall[j1 * HDIM + tid] = v1;
                ld_gall[j2 * HDIM + tid] = v2;
            } else {
                ld_gall[j0 * HDIM + tid] =
                    __hip_atomic_load(&gws[(gbase + 8 * j0) * HDIM + tid],
                                      __ATOMIC_RELAXED, __HIP_MEMORY_SCOPE_AGENT);
                ld_gall[j1 * HDIM + tid] =
                    __hip_atomic_load(&gws[(gbase + 8 * j1) * HDIM + tid],
                                      __ATOMIC_RELAXED, __HIP_MEMORY_SCOPE_AGENT);
                ld_gall[j2 * HDIM + tid] =
                    __hip_atomic_load(&gws[(gbase + 8 * j2) * HDIM + tid],
                                      __ATOMIC_RELAXED, __HIP_MEMORY_SCOPE_AGENT);
            }
            __syncthreads();
            // ---- matvec: my 128-col slice x 4 batches, rotated 32-row window ----
            {
                const float4* Wb = Wsl + (size_t)blk * HDIM * 128;
                float4 acc[4];
                #pragma unroll
                for (int bi = 0; bi < 4; ++bi) acc[bi] = make_float4(0.f, 0.f, 0.f, 0.f);
                float4 a0 = Wb[(size_t)(base_row)     * 128];
                float4 a1 = Wb[(size_t)(base_row + 1) * 128];
                #pragma unroll 2
                for (int rr = 0; rr < 32; rr += 4) {
                    int rB = base_row + ((rr + 2) & 31);
                    float4 b0 = Wb[(size_t)rB * 128];
                    float4 b1 = Wb[(size_t)(rB + 1) * 128];
                    {
                        int r = base_row + rr;
                        #pragma unroll
                        for (int bi = 0; bi < 4; ++bi) {
                            float g0 = ld_gall[bi * HDIM + r];
                            float g1 = ld_gall[bi * HDIM + r + 1];
                            acc[bi].x = fmaf(g1, a1.x, fmaf(g0, a0.x, acc[bi].x));
                            acc[bi].y = fmaf(g1, a1.y, fmaf(g0, a0.y, acc[bi].y));
                            acc[bi].z = fmaf(g1, a1.z, fmaf(g0, a0.z, acc[bi].z));
                            acc[bi].w = fmaf(g1, a1.w, fmaf(g0, a0.w, acc[bi].w));
                        }
                    }
                    int rA = base_row + ((rr + 4) & 31);
                    a0 = Wb[(size_t)rA * 128];
                    a1 = Wb[(size_t)(rA + 1) * 128];
                    {
                        int r = base_row + rr + 2;
                        #pragma unroll
                        for (int bi = 0; bi < 4; ++bi) {
                            float g0 = ld_gall[bi * HDIM + r];
                            float g1 = ld_gall[bi * HDIM + r + 1];
                            acc[bi].x = fmaf(g1, b1.x, fmaf(g0, b0.x, acc[bi].x));
                            acc[bi].y = fmaf(g1, b1.y, fmaf(g0, b0.y, acc[bi].y));
                            acc[bi].z = fmaf(g1, b1.z, fmaf(g0, b0.z, acc[bi].z));
                            acc[bi].w = fmaf(g1, b1.w, fmaf(g0, b0.w, acc[bi].w));
                        }
                    }
                }
                #pragma unroll
                for (int bi = 0; bi < 4; ++bi)
                    ld_z4[(rg * 4 + bi) * 32 + c4] = acc[bi];
            }
            __syncthreads();
            // ---- reduce 16 row-group partials, ship slices to owners ----
            {
                const float* zf = (const float*)ld_z4;
                int bi2 = tid >> 7;        // group member index
                int col = tid & 127;
                float zv = 0.f;
                #pragma unroll
                for (int k = 0; k < 16; ++k) zv += zf[(k * 4 + bi2) * 128 + col];
                float* zp = &zws[(gbase + 8 * bi2) * HDIM + mem * 128 + col];
                if (fast) *zp = zv;
                else __hip_atomic_store(zp, zv, __ATOMIC_RELAXED, __HIP_MEMORY_SCOPE_AGENT);
            }
            __syncthreads();
            if (tid == 4)
                __hip_atomic_store(&fz[b], seq, __ATOMIC_RELAXED, __HIP_MEMORY_SCOPE_AGENT);
            if (tid < 3) {
                int j = tid + (tid >= mem ? 1 : 0);
                while (__hip_atomic_load(&fz[gbase + 8 * j],
                                         __ATOMIC_RELAXED, __HIP_MEMORY_SCOPE_AGENT) < seq)
                    __builtin_amdgcn_s_sleep(1);
            }
            __syncthreads();
            // ---- read own full z, residual + one-pass LN ----
            {
                float zraw = fast ? load1_l2(&zws[b * HDIM + tid])
                                  : __hip_atomic_load(&zws[b * HDIM + tid],
                                                      __ATOMIC_RELAXED,
                                                      __HIP_MEMORY_SCOPE_AGENT);
                float z = zraw + (blk ? ob1 : ob0);
                float res = (i == 0) ? dpv : z;    // ref: residual=proj @ i==0
                float tmp = z + res;
                float v1 = tmp, v2 = tmp * tmp;
                #pragma unroll
                for (int m = 1; m < 64; m <<= 1) {
                    v1 += __shfl_xor(v1, m);
                    v2 += __shfl_xor(v2, m);
                }
                if ((tid & 63) == 0) {
                    ld_red[2 * (tid >> 6)]     = v1;
                    ld_red[2 * (tid >> 6) + 1] = v2;
                }
                __syncthreads();
                float s1r = 0.f, s2r = 0.f;
                #pragma unroll
                for (int q = 0; q < 8; ++q) { s1r += ld_red[2*q]; s2r += ld_red[2*q+1]; }
                float mu  = s1r * (1.f / 512.f);
                float var = s2r * (1.f / 512.f) - mu * mu;
                float rs  = rsqrtf(var + 1e-5f);
                __syncthreads();           // red consumed; xd safe to overwrite
                ld_xd[tid] = (tmp - mu) * rs * (blk ? lg1 : lg0) + (blk ? lb1 : lb0);
                __syncthreads();
            }
        }

        // ================= head #1 =================
        {
            float v = ld_xd[tid] + ctxr;
            const float* w = headW + tid * ODIM;
            float p[ODIM];
            #pragma unroll
            for (int o = 0; o < ODIM; ++o) p[o] = v * w[o];
            #pragma unroll
            for (int m = 1; m < 64; m <<= 1) {
                #pragma unroll
                for (int o = 0; o < ODIM; ++o) p[o] += __shfl_xor(p[o], m);
            }
            if ((tid & 63) == 0) {
                int wv = tid >> 6;
                #pragma unroll
                for (int o = 0; o < ODIM; ++o) ld_hred[wv * ODIM + o] = p[o];
            }
            __syncthreads();
            if (tid < ODIM) {
                float s = headb[tid];
                #pragma unroll
                for (int wv = 0; wv < 8; ++wv) s += ld_hred[wv * ODIM + tid];
                ld_logit[tid] = s;
            }
            __syncthreads();
        }

        const bool is_out = ((i & 1) == 0);
        if (is_out) {
            if (tid < ODIM)
                out[(b * TSTEPS + i) * ODIM + tid] = sig32(ld_logit[tid]);
            if (tid == 0) {
                float nc = (sig32(ld_logit[0]) > 0.5f) ? 1.f : 0.f;
                ld_dec[0] = nc; ld_dec[1] = 1.f; ld_dec[2] = 0.f;
            }
            __syncthreads();
        } else {
            // np.argmax over f32 SIGMOIDS (saturation => not logit-argmax!)
            if (tid == 0) {
                int best = 0; float bv = sig32(ld_logit[3]);
                #pragma unroll
                for (int o = 1; o < 6; ++o) {
                    float v2 = sig32(ld_logit[3 + o]);
                    if (v2 > bv) { bv = v2; best = o; }
                }
                ld_ptr = best;
                ld_dec[0] = 0.f; ld_dec[1] = 0.f; ld_dec[2] = 1.f;
            }
            __syncthreads();
            {   // ctx += encoded[b, ptr, :]
                const float* iseq = input_seq + (b * SEQ + ld_ptr) * 3;
                float e0 = iseq[0], e1 = iseq[1], e2 = iseq[2];
                ctxr += fmaf(e0, w0, fmaf(e1, w1, fmaf(e2, w2, inb_t)));
            }
            __syncthreads();
            // ================= head #2 =================
            {
                float v = ld_xd[tid] + ctxr;
                const float* w = headW + tid * ODIM;
                float p[ODIM];
                #pragma unroll
                for (int o = 0; o < ODIM; ++o) p[o] = v * w[o];
                #pragma unroll
                for (int m = 1; m < 64; m <<= 1) {
                    #pragma unroll
                    for (int o = 0; o < ODIM; ++o) p[o] += __shfl_xor(p[o], m);
                }
                if ((tid & 63) == 0) {
                    int wv = tid >> 6;
                    #pragma unroll
                    for (int o = 0; o < ODIM; ++o) ld_hred[wv * ODIM + o] = p[o];
                }
                __syncthreads();
                if (tid < ODIM) {
                    float s = headb[tid];
                    #pragma unroll
                    for (int wv = 0; wv < 8; ++wv) s += ld_hred[wv * ODIM + tid];
                    out[(b * TSTEPS + i) * ODIM + tid] = sig32(s);
                }
            }
            __syncthreads();
        }
    }
}

extern "C" void kernel_launch(void* const* d_in, const int* in_sizes, int n_in,
                              void* d_out, int out_size, void* d_ws, size_t ws_size,
                              hipStream_t stream) {
    (void)in_sizes; (void)n_in; (void)ws_size; (void)out_size;
    const float* input_seq = (const float*)d_in[0];
    // d_in[1] = autoregressive_steps (scalar) -- T fixed at 63 by the model
    const float* in_W   = (const float*)d_in[2];
    const float* in_b   = (const float*)d_in[3];
    const float* Aarr   = (const float*)d_in[4];
    const float* Barr   = (const float*)d_in[5];
    const float* Carr   = (const float*)d_in[6];
    const float* Darr   = (const float*)d_in[7];
    const float* outW   = (const float*)d_in[8];
    const float* outb   = (const float*)d_in[9];
    const float* ln_g   = (const float*)d_in[10];
    const float* ln_b   = (const float*)d_in[11];
    const float* headW  = (const float*)d_in[12];
    const float* headb  = (const float*)d_in[13];
    float* out = (float*)d_out;

    // ws layout: fg [0,1K), fz [1K,2K), fx [2K,3K), xid [3K,4K), gws, zws
    unsigned* fg  = (unsigned*)d_ws;
    unsigned* fz  = fg + BATCH;
    unsigned* fx  = fz + BATCH;
    unsigned* xid = fx + BATCH;
    float* gws = (float*)((char*)d_ws + 4096);
    float* zws = gws + BATCH * HDIM;

    // zero all flags every launch (ws is poisoned 0xAA by the harness)
    hipMemsetAsync(d_ws, 0, 4096, stream);

    s4_decode_kernel<<<BATCH, NTHR, 0, stream>>>(
        input_seq, in_W, in_b, Aarr, Barr, Carr, Darr,
        outW, outb, ln_g, ln_b, headW, headb, out,
        gws, zws, fg, fz, fx, xid);
}